// Round 24
// baseline (373.076 us; speedup 1.0000x reference)
//
#include <hip/hip_runtime.h>
#include <hip/hip_bf16.h>

#define N_NODES 50000
#define NUM_FEAT 2000
#define HEADS 8
#define HID 8
#define NUM_CLASSES 30
#define NUM_EDGES 1600000
#define E_TOTAL (NUM_EDGES + N_NODES)
#define E8 (E_TOTAL * 8)
#define KT32 64
#define KT64 32
#define ROWCAP 128            // fixed per-node CSR capacity (max deg ~67)
#define GEMM_BLOCKS ((N_NODES + 63) / 64)          // 782
#define FILL_BLOCKS ((E_TOTAL + 255) / 256)        // 6446
#define L2_BLOCKS ((N_NODES + 3) / 4)              // 12500
#define A1_BLOCKS ((E8 + 255) / 256)               // 51719
#define LOG2E 1.44269504f
#define SENT N_NODES          // sentinel node id (fits ushort)
#define NEG_BIG -1.0e30f

typedef __attribute__((ext_vector_type(8))) short short8;
typedef __attribute__((ext_vector_type(8))) unsigned short ushort8;
typedef __attribute__((ext_vector_type(4))) float f32x4;

typedef __attribute__((address_space(1))) const unsigned int gu32;
typedef __attribute__((address_space(3))) unsigned int lu32;

__device__ __forceinline__ void gload_lds16(const void* g, void* l) {
  __builtin_amdgcn_global_load_lds((gu32*)g, (lu32*)l, 16, 0, 0);
}

__device__ __forceinline__ ushort f2bf(float f) {
  __hip_bfloat16 b = __float2bfloat16(f);
  return *reinterpret_cast<ushort*>(&b);
}

__device__ __forceinline__ float bf2f(ushort u) {
  unsigned int x = ((unsigned int)u) << 16;
  union { unsigned int i; float f; } c; c.i = x;
  return c.f;
}

__device__ __forceinline__ float lexp2(float sc) {   // exp2(leaky(sc)); sc pre-scaled by log2e
  return exp2f(fmaxf(sc, 0.2f * sc));
}

__device__ __forceinline__ short8 cvt8(float4 a, float4 b) {
  union { short8 v; ushort u[8]; } p;
  p.u[0] = f2bf(a.x); p.u[1] = f2bf(a.y); p.u[2] = f2bf(a.z); p.u[3] = f2bf(a.w);
  p.u[4] = f2bf(b.x); p.u[5] = f2bf(b.y); p.u[6] = f2bf(b.z); p.u[7] = f2bf(b.w);
  return p.v;
}

// ---- fused init: sentinel prefill + weight pack + cursor zero + sentinels ---
__global__ __launch_bounds__(256) void k_init(ushort* __restrict__ esrc,
    const float* __restrict__ Wres, const float* __restrict__ W1,
    ushort* __restrict__ Bp, int* __restrict__ cursor,
    ushort* __restrict__ Hatt, float* __restrict__ a_src1) {
  int i = blockIdx.x * 256 + threadIdx.x;
  const unsigned rep = (unsigned)SENT | ((unsigned)SENT << 16);
  if (i < N_NODES * ROWCAP / 8)
    ((uint4*)esrc)[i] = make_uint4(rep, rep, rep, rep);
  if (i < N_NODES / 4)
    *(int4*)&cursor[i * 4] = make_int4(0, 0, 0, 0);
  if (i < KT32 * 4 * 128) {
    int col = i & 127;
    int kbase = (i >> 7) * 8;
    const float* W = (col < 64) ? Wres : W1;
    int c = col & 63;
    union { short8 v; ushort u[8]; } p;
#pragma unroll
    for (int j = 0; j < 8; ++j) {
      int k = kbase + j;
      p.u[j] = f2bf(k < NUM_FEAT ? W[(size_t)k * 64 + c] : 0.f);
    }
    *(short8*)&Bp[(size_t)i * 8] = p.v;
  }
  // static sentinel rows (node SENT never written by GEMM)
  if (i < 64) Hatt[(size_t)SENT * 64 + i] = 0;
  if (i >= 64 && i < 72) a_src1[SENT * 8 + (i - 64)] = NEG_BIG;
}

// ---- MFMA GEMM + concurrent CSR fill + fused attn1 logits -------------------
// GEMM: 3-buffer LDS rotation, B-DMA and A-prefetch both 2 steps deep.
// Barrier waits vmcnt(12) = drain B(t+1) only (issued a full step earlier);
// A(t) is waited by the compiler at cvt8, ~2 steps after issue.
__global__ __launch_bounds__(256) void k_gemm_fill(const float* __restrict__ X,
    const ushort* __restrict__ Bp, const float* __restrict__ brs,
    const float* __restrict__ b1, float* __restrict__ Hres,
    ushort* __restrict__ Hatt, const int* __restrict__ ei,
    int* __restrict__ cursor, ushort* __restrict__ esrc,
    const float* __restrict__ att_src1, const float* __restrict__ att_dst1,
    float* __restrict__ a_src, float2* __restrict__ dinv1) {
  __shared__ ushort ldsB[3][8192];
  if (blockIdx.x >= GEMM_BLOCKS) {                 // ---- fill path ----
    int e = (blockIdx.x - GEMM_BLOCKS) * 256 + threadIdx.x;
    if (e < E_TOTAL) {
      int s, d;
      if (e < NUM_EDGES) { s = ei[e]; d = ei[NUM_EDGES + e]; }
      else { s = d = e - NUM_EDGES; }
      int pos = atomicAdd(&cursor[d], 1);
      esrc[(unsigned)(d * ROWCAP + pos)] = (ushort)s;
    }
    return;
  }
  // ---- GEMM path ----
  const int tid = threadIdx.x;
  const int lane = tid & 63, wid = tid >> 6;
  const int lg = lane >> 4, lr = lane & 15;
  const int m0 = blockIdx.x * 64;

  int rowg = m0 + wid * 16 + lr;
  rowg = rowg < N_NODES ? rowg : N_NODES - 1;
  const float* axp = X + (size_t)rowg * NUM_FEAT + lg * 8;

  f32x4 acc[8] = {};
  float4 a[4], na[4], nna[4];
  const float4 fz = make_float4(0.f, 0.f, 0.f, 0.f);

  auto loadA = [&](int t, float4* r) {
#pragma unroll
    for (int s = 0; s < 2; ++s) {
      int k0 = t * 64 + s * 32 + lg * 8;
      if (k0 < NUM_FEAT) {
        r[2 * s]     = *(const float4*)(axp + t * 64 + s * 32);
        r[2 * s + 1] = *(const float4*)(axp + t * 64 + s * 32 + 4);
      } else { r[2 * s] = fz; r[2 * s + 1] = fz; }
    }
  };
  auto dmaB = [&](int t, int buf) {
#pragma unroll
    for (int q = 0; q < 4; ++q) {
      const ushort* g = Bp + ((size_t)t * 1024 + q * 256 + wid * 64 + lane) * 8;
      gload_lds16(g, &ldsB[buf][(size_t)(q * 256 + wid * 64) * 8]);
    }
  };
  auto mfmaStep = [&](int cur, const float4* av) {
#pragma unroll
    for (int s = 0; s < 2; ++s) {
      short8 fb[8];
#pragma unroll
      for (int n = 0; n < 8; ++n)
        fb[n] = *(const short8*)&ldsB[cur][(size_t)(s * 512 + lg * 128 + n * 16 + lr) * 8];
      short8 fa = cvt8(av[2 * s], av[2 * s + 1]);
#pragma unroll
      for (int n = 0; n < 8; ++n)
        acc[n] = __builtin_amdgcn_mfma_f32_16x16x32_bf16(fa, fb[n], acc[n], 0, 0, 0);
    }
  };

  // prologue: B(0),B(1) DMA'd; A(0),A(1) in flight
  dmaB(0, 0);
  __builtin_amdgcn_sched_barrier(0);
  loadA(0, a);
  dmaB(1, 1);
  __builtin_amdgcn_sched_barrier(0);
  loadA(1, na);
  asm volatile("s_waitcnt vmcnt(12)" ::: "memory");  // drain B(0)
  __builtin_amdgcn_s_barrier();
  __builtin_amdgcn_sched_barrier(0);

  int cur = 0, nxt1 = 1, nxt2 = 2;
  for (int t = 0; t < KT64 - 2; ++t) {
    dmaB(t + 2, nxt2);                               // 4 DMA, 2 steps ahead
    __builtin_amdgcn_sched_barrier(0);
    loadA(t + 2, nna);                               // 4 HBM loads, 2 ahead
    mfmaStep(cur, a);                                // compiler waits A(t)
    asm volatile("s_waitcnt vmcnt(12)" ::: "memory"); // drain B(t+1) only
    __builtin_amdgcn_s_barrier();
    __builtin_amdgcn_sched_barrier(0);
#pragma unroll
    for (int q = 0; q < 4; ++q) { a[q] = na[q]; na[q] = nna[q]; }
    int tmp = cur; cur = nxt1; nxt1 = nxt2; nxt2 = tmp;
  }
  // step KT64-2: nothing new issued; drain B(KT64-1)
  mfmaStep(cur, a);
  asm volatile("s_waitcnt vmcnt(4)" ::: "memory");   // only A(KT64-1) newer
  __builtin_amdgcn_s_barrier();
  __builtin_amdgcn_sched_barrier(0);
#pragma unroll
  for (int q = 0; q < 4; ++q) a[q] = na[q];
  mfmaStep(nxt1, a);                                 // final step

  // epilogue: C/D map col=lane&15, row=(lane>>4)*4+i  [m89-verified]
#pragma unroll
  for (int n = 0; n < 8; ++n) {
    int col = n * 16 + lr;
    if (col < 64) {
      float badd = brs[col] + b1[col];
#pragma unroll
      for (int i = 0; i < 4; ++i) {
        int row = m0 + wid * 16 + lg * 4 + i;
        if (row < N_NODES) Hres[(size_t)row * 64 + col] = acc[n][i] + badd;
      }
    } else {
#pragma unroll
      for (int i = 0; i < 4; ++i) {
        int row = m0 + wid * 16 + lg * 4 + i;
        if (row < N_NODES) Hatt[(size_t)row * 64 + (col - 64)] = f2bf(acc[n][i]);
      }
    }
  }
  // fused attn1 logits: head h = ((n-4)*16+lr)>>3, channel c = lr&7.
#pragma unroll
  for (int n = 4; n < 8; ++n) {
    int acol = (n - 4) * 16 + lr;
    int h = acol >> 3, c = acol & 7;
    float wsrc = att_src1[h * 8 + c];
    float wdst = att_dst1[h * 8 + c];
#pragma unroll
    for (int i = 0; i < 4; ++i) {
      float v = acc[n][i];
      float s = v * wsrc, d = v * wdst;
      s += __shfl_xor(s, 1); s += __shfl_xor(s, 2); s += __shfl_xor(s, 4);
      d += __shfl_xor(d, 1); d += __shfl_xor(d, 2); d += __shfl_xor(d, 4);
      int row = m0 + wid * 16 + lg * 4 + i;
      if ((lane & 7) == 0 && row < N_NODES) {
        a_src[(unsigned)(row * 8 + h)] = s * LOG2E;
        dinv1[(unsigned)(row * 8 + h)] = make_float2(d * LOG2E, 0.f);
      }
    }
  }
}

// ---------------- layer-1 aggregation FUSED with layer-2 prep ---------------
__global__ __launch_bounds__(256) void k_layer1f(const ushort* __restrict__ esrc,
    const int* __restrict__ cursor,
    const float* __restrict__ Hres, const ushort* __restrict__ Hatt,
    const float* __restrict__ a_src, float2* __restrict__ dinv1,
    const float* __restrict__ w2, const float* __restrict__ att_src2,
    const float* __restrict__ att_dst2, ushort* __restrict__ h2b,
    float* __restrict__ a_src2, float2* __restrict__ dinv2) {
  __shared__ float w2s[64 * 30];
  __shared__ float xs[4][64];
  for (int i = threadIdx.x; i < 64 * 30; i += 256) w2s[i] = w2[i];
  if (blockIdx.x == 0) {
    if (threadIdx.x < 32) h2b[(unsigned)(SENT * 32 + threadIdx.x)] = 0;
    if (threadIdx.x == 32) a_src2[SENT] = NEG_BIG;
  }
  __syncthreads();
  int wave = threadIdx.x >> 6, lane = threadIdx.x & 63;
  int n = blockIdx.x * 4 + wave;
  if (n >= N_NODES) return;
  int hd = lane >> 3;
  int eo = lane & 7;
  float adn = dinv1[(unsigned)(n * 8 + hd)].x;
  int start = n * ROWCAP, end = start + ((cursor[n] + 7) & ~7);
  float denom = 0.f, msg = 0.f;
  for (int p = start; p < end; p += 8) {
    unsigned sl = esrc[p + eo];
    float evm = lexp2(a_src[sl * 8 + hd] + adn);
    ushort8 v = *(const ushort8*)&esrc[p];
    ushort hu[8];
#pragma unroll
    for (int i = 0; i < 8; ++i) hu[i] = Hatt[(unsigned)v[i] * 64 + lane];
#pragma unroll
    for (int i = 0; i < 8; ++i) {
      float ev = __shfl(evm, hd * 8 + i);
      denom += ev;
      msg = fmaf(ev, bf2f(hu[i]), msg);
    }
  }
  float invd = 1.f / (denom + 1e-16f);
  float x1v = msg * invd + Hres[(unsigned)(n * 64 + lane)];
  x1v = x1v > 0.f ? x1v : __expf(x1v) - 1.f;
  if (eo == 0) dinv1[(unsigned)(n * 8 + hd)].y = invd;

  xs[wave][lane] = x1v;
  float acc2 = 0.f;
  if (lane < 30) {
#pragma unroll 8
    for (int k = 0; k < 64; ++k) acc2 = fmaf(xs[wave][k], w2s[k * 30 + lane], acc2);
  }
  float as = (lane < 30) ? acc2 * att_src2[lane] : 0.f;
  float ad = (lane < 30) ? acc2 * att_dst2[lane] : 0.f;
  for (int off = 1; off < 64; off <<= 1) {
    as += __shfl_xor(as, off);
    ad += __shfl_xor(ad, off);
  }
  if (lane == 0) { a_src2[n] = as * LOG2E; dinv2[n] = make_float2(ad * LOG2E, 0.f); }
  if (lane < 32) h2b[(unsigned)(n * 32 + lane)] = (lane < 30) ? f2bf(acc2) : (ushort)0;
}

// ---------------- layer-2 aggregation + concurrent alpha1 -------------------
__global__ __launch_bounds__(256) void k_l2a1(const ushort* __restrict__ esrc,
    const int* __restrict__ cursor,
    const ushort* __restrict__ h2b, const float* __restrict__ a_src2,
    float2* __restrict__ dinv2, const float* __restrict__ b2,
    float* __restrict__ out0, const int* __restrict__ ei,
    const float* __restrict__ a_src1, const float2* __restrict__ dinv1,
    float* __restrict__ alpha1) {
  if (blockIdx.x >= L2_BLOCKS) {                   // ---- alpha1 path ----
    int i = (blockIdx.x - L2_BLOCKS) * 256 + threadIdx.x;
    if (i < E8) {
      int e = i >> 3, h = i & 7;
      int s, d;
      if (e < NUM_EDGES) { s = ei[e]; d = ei[NUM_EDGES + e]; }
      else { s = d = e - NUM_EDGES; }
      float2 di = dinv1[(unsigned)(d * 8 + h)];
      alpha1[i] = lexp2(a_src1[(unsigned)(s * 8 + h)] + di.x) * di.y;
    }
    return;
  }
  // ---- layer-2 path ----
  int wave = threadIdx.x >> 6, lane = threadIdx.x & 63;
  int n = blockIdx.x * 4 + wave;
  if (n >= N_NODES) return;
  float adn = dinv2[n].x;
  int start = n * ROWCAP, end = start + ((cursor[n] + 7) & ~7);
  int cls = lane & 31;
  float denom = 0.f, msg = 0.f;
  for (int p = start; p < end; p += 8) {
    unsigned sl = esrc[p + (lane & 7)];
    float evm = lexp2(a_src2[sl] + adn);
    ushort8 v = *(const ushort8*)&esrc[p];
    ushort hv[8];
#pragma unroll
    for (int i = 0; i < 8; ++i) hv[i] = h2b[(unsigned)v[i] * 32 + cls];
#pragma unroll
    for (int i = 0; i < 8; ++i) {
      float ev = __shfl(evm, i);
      denom += ev;
      msg = fmaf(ev, bf2f(hv[i]), msg);
    }
  }
  float invd = 1.f / (denom + 1e-16f);
  bool act = lane < 30;
  float o = act ? msg * invd + b2[lane] : 0.f;
  float x2 = o > 0.f ? o : __expf(o) - 1.f;
  float mv = act ? x2 : -1e30f;
  for (int off = 1; off < 64; off <<= 1) mv = fmaxf(mv, __shfl_xor(mv, off));
  float ex = act ? __expf(x2 - mv) : 0.f;
  for (int off = 1; off < 64; off <<= 1) ex += __shfl_xor(ex, off);
  if (act) out0[(size_t)n * 30 + lane] = x2 - mv - __logf(ex);
  if (lane == 0) dinv2[n].y = invd;
}

// ---------------- alpha2: edge-order, coalesced -----------------------------
__global__ __launch_bounds__(256) void k_alpha2(const int* __restrict__ ei,
    const float* __restrict__ a_src2, const float2* __restrict__ dinv2,
    float* __restrict__ alpha2) {
  int i = blockIdx.x * 256 + threadIdx.x;
  if (i >= E_TOTAL) return;
  int s, d;
  if (i < NUM_EDGES) { s = ei[i]; d = ei[NUM_EDGES + i]; }
  else { s = d = i - NUM_EDGES; }
  float2 dj = dinv2[(unsigned)d];
  alpha2[i] = lexp2(a_src2[(unsigned)s] + dj.x) * dj.y;
}

extern "C" void kernel_launch(void* const* d_in, const int* in_sizes, int n_in,
                              void* d_out, int out_size, void* d_ws, size_t ws_size,
                              hipStream_t stream) {
  const float* x        = (const float*)d_in[0];
  const int*   ei       = (const int*)d_in[1];
  const float* w_res    = (const float*)d_in[2];
  const float* b_res    = (const float*)d_in[3];
  const float* w1       = (const float*)d_in[4];
  const float* att_src1 = (const float*)d_in[5];
  const float* att_dst1 = (const float*)d_in[6];
  const float* b1       = (const float*)d_in[7];
  const float* w2       = (const float*)d_in[8];
  const float* att_src2 = (const float*)d_in[9];
  const float* att_dst2 = (const float*)d_in[10];
  const float* b2       = (const float*)d_in[11];

  float* ws = (float*)d_ws;
  float* Hres    = ws;                                     // [N][64]  12.8 MB
  ushort* esrc   = (ushort*)(Hres + (size_t)N_NODES * 64); // [N][128] ushort 12.8 MB
  float* a_src1  = (float*)(esrc + (size_t)N_NODES * ROWCAP); // [(N+1)][8]
  float2* dinv1  = (float2*)(a_src1 + (size_t)(N_NODES + 1) * 8); // [N][8]
  float* a_src2  = (float*)(dinv1 + (size_t)N_NODES * 8);  // [N+1]
  float2* dinv2  = (float2*)(a_src2 + N_NODES + 1);        // [N]
  ushort* Hatt   = (ushort*)(dinv2 + N_NODES);             // [(N+1)][64]
  ushort* h2b    = Hatt + (size_t)(N_NODES + 1) * 64;      // [(N+1)][32]
  ushort* Bp     = h2b + (size_t)(N_NODES + 1) * 32 + 32;  // 1 MB
  int*   cursor  = (int*)(Bp + (size_t)KT32 * 4096 + 64);  // [N]

  float* out0   = (float*)d_out;                           // [N][30]
  float* alpha1 = out0 + (size_t)N_NODES * 30;             // [E_TOTAL][8]
  float* alpha2 = alpha1 + (size_t)E8;                     // [E_TOTAL]

  k_init<<<(N_NODES * ROWCAP / 8 + 255) / 256, 256, 0, stream>>>(esrc, w_res, w1,
                                                                 Bp, cursor,
                                                                 Hatt, a_src1);
  k_gemm_fill<<<GEMM_BLOCKS + FILL_BLOCKS, 256, 0, stream>>>(x, Bp, b_res, b1,
                                                             Hres, Hatt, ei,
                                                             cursor, esrc,
                                                             att_src1, att_dst1,
                                                             a_src1, dinv1);
  k_layer1f<<<(N_NODES + 3) / 4, 256, 0, stream>>>(esrc, cursor, Hres, Hatt,
                                                   a_src1, dinv1, w2, att_src2,
                                                   att_dst2, h2b, a_src2, dinv2);
  k_l2a1<<<L2_BLOCKS + A1_BLOCKS, 256, 0, stream>>>(esrc, cursor, h2b, a_src2,
                                                    dinv2, b2, out0, ei,
                                                    a_src1, dinv1, alpha1);
  k_alpha2<<<(E_TOTAL + 255) / 256, 256, 0, stream>>>(ei, a_src2, dinv2, alpha2);
}

// Round 25
// 350.344 us; speedup vs baseline: 1.0649x; 1.0649x over previous
//
#include <hip/hip_runtime.h>
#include <hip/hip_bf16.h>

#define N_NODES 50000
#define NUM_FEAT 2000
#define HEADS 8
#define HID 8
#define NUM_CLASSES 30
#define NUM_EDGES 1600000
#define E_TOTAL (NUM_EDGES + N_NODES)
#define E8 (E_TOTAL * 8)
#define KT32 64
#define KT64 32
#define ROWCAP 128            // fixed per-node CSR capacity (max deg ~67)
#define GEMM_BLOCKS ((N_NODES + 63) / 64)          // 782
#define FILL_BLOCKS ((E_TOTAL + 255) / 256)        // 6446
#define L2_BLOCKS ((N_NODES + 3) / 4)              // 12500
#define A1_BLOCKS ((E8 + 255) / 256)               // 51719
#define LOG2E 1.44269504f
#define SENT N_NODES          // sentinel node id (fits ushort)
#define NEG_BIG -1.0e30f

typedef __attribute__((ext_vector_type(8))) short short8;
typedef __attribute__((ext_vector_type(8))) unsigned short ushort8;
typedef __attribute__((ext_vector_type(4))) float f32x4;

typedef __attribute__((address_space(1))) const unsigned int gu32;
typedef __attribute__((address_space(3))) unsigned int lu32;

__device__ __forceinline__ void gload_lds16(const void* g, void* l) {
  __builtin_amdgcn_global_load_lds((gu32*)g, (lu32*)l, 16, 0, 0);
}

__device__ __forceinline__ ushort f2bf(float f) {
  __hip_bfloat16 b = __float2bfloat16(f);
  return *reinterpret_cast<ushort*>(&b);
}

__device__ __forceinline__ float bf2f(ushort u) {
  unsigned int x = ((unsigned int)u) << 16;
  union { unsigned int i; float f; } c; c.i = x;
  return c.f;
}

__device__ __forceinline__ float lexp2(float sc) {   // exp2(leaky(sc)); sc pre-scaled by log2e
  return exp2f(fmaxf(sc, 0.2f * sc));
}

__device__ __forceinline__ short8 cvt8(float4 a, float4 b) {
  union { short8 v; ushort u[8]; } p;
  p.u[0] = f2bf(a.x); p.u[1] = f2bf(a.y); p.u[2] = f2bf(a.z); p.u[3] = f2bf(a.w);
  p.u[4] = f2bf(b.x); p.u[5] = f2bf(b.y); p.u[6] = f2bf(b.z); p.u[7] = f2bf(b.w);
  return p.v;
}

// ---- fused init: sentinel prefill + weight pack + cursor zero + sentinels ---
__global__ __launch_bounds__(256) void k_init(ushort* __restrict__ esrc,
    const float* __restrict__ Wres, const float* __restrict__ W1,
    ushort* __restrict__ Bp, int* __restrict__ cursor,
    ushort* __restrict__ Hatt, float* __restrict__ a_src1) {
  int i = blockIdx.x * 256 + threadIdx.x;
  const unsigned rep = (unsigned)SENT | ((unsigned)SENT << 16);
  if (i < N_NODES * ROWCAP / 8)
    ((uint4*)esrc)[i] = make_uint4(rep, rep, rep, rep);
  if (i < N_NODES / 4)
    *(int4*)&cursor[i * 4] = make_int4(0, 0, 0, 0);
  if (i < KT32 * 4 * 128) {
    int col = i & 127;
    int kbase = (i >> 7) * 8;
    const float* W = (col < 64) ? Wres : W1;
    int c = col & 63;
    union { short8 v; ushort u[8]; } p;
#pragma unroll
    for (int j = 0; j < 8; ++j) {
      int k = kbase + j;
      p.u[j] = f2bf(k < NUM_FEAT ? W[(size_t)k * 64 + c] : 0.f);
    }
    *(short8*)&Bp[(size_t)i * 8] = p.v;
  }
  // static sentinel rows (node SENT never written by GEMM)
  if (i < 64) Hatt[(size_t)SENT * 64 + i] = 0;
  if (i >= 64 && i < 72) a_src1[SENT * 8 + (i - 64)] = NEG_BIG;
}

// ---- MFMA GEMM + concurrent CSR fill + fused attn1 logits -------------------
__global__ __launch_bounds__(256) void k_gemm_fill(const float* __restrict__ X,
    const ushort* __restrict__ Bp, const float* __restrict__ brs,
    const float* __restrict__ b1, float* __restrict__ Hres,
    ushort* __restrict__ Hatt, const int* __restrict__ ei,
    int* __restrict__ cursor, ushort* __restrict__ esrc,
    const float* __restrict__ att_src1, const float* __restrict__ att_dst1,
    float* __restrict__ a_src, float2* __restrict__ dinv1) {
  __shared__ ushort ldsB[2][8192];
  if (blockIdx.x >= GEMM_BLOCKS) {                 // ---- fill path ----
    int e = (blockIdx.x - GEMM_BLOCKS) * 256 + threadIdx.x;
    if (e < E_TOTAL) {
      int s, d;
      if (e < NUM_EDGES) { s = ei[e]; d = ei[NUM_EDGES + e]; }
      else { s = d = e - NUM_EDGES; }
      int pos = atomicAdd(&cursor[d], 1);
      esrc[(unsigned)(d * ROWCAP + pos)] = (ushort)s;
    }
    return;
  }
  // ---- GEMM path ----
  const int tid = threadIdx.x;
  const int lane = tid & 63, wid = tid >> 6;
  const int lg = lane >> 4, lr = lane & 15;
  const int m0 = blockIdx.x * 64;

  int rowg = m0 + wid * 16 + lr;
  rowg = rowg < N_NODES ? rowg : N_NODES - 1;
  const float* axp = X + (size_t)rowg * NUM_FEAT + lg * 8;

  f32x4 acc[8] = {};
  float4 a[4], na[4];
  const float4 fz = make_float4(0.f, 0.f, 0.f, 0.f);

  auto loadA = [&](int t, float4* r) {
#pragma unroll
    for (int s = 0; s < 2; ++s) {
      int k0 = t * 64 + s * 32 + lg * 8;
      if (k0 < NUM_FEAT) {
        r[2 * s]     = *(const float4*)(axp + t * 64 + s * 32);
        r[2 * s + 1] = *(const float4*)(axp + t * 64 + s * 32 + 4);
      } else { r[2 * s] = fz; r[2 * s + 1] = fz; }
    }
  };
  auto dmaB = [&](int t, int buf) {
#pragma unroll
    for (int q = 0; q < 4; ++q) {
      const ushort* g = Bp + ((size_t)t * 1024 + q * 256 + wid * 64 + lane) * 8;
      gload_lds16(g, &ldsB[buf][(size_t)(q * 256 + wid * 64) * 8]);
    }
  };
  auto mfmaStep = [&](int cur, const float4* av) {
#pragma unroll
    for (int s = 0; s < 2; ++s) {
      short8 fb[8];
#pragma unroll
      for (int n = 0; n < 8; ++n)
        fb[n] = *(const short8*)&ldsB[cur][(size_t)(s * 512 + lg * 128 + n * 16 + lr) * 8];
      short8 fa = cvt8(av[2 * s], av[2 * s + 1]);
#pragma unroll
      for (int n = 0; n < 8; ++n)
        acc[n] = __builtin_amdgcn_mfma_f32_16x16x32_bf16(fa, fb[n], acc[n], 0, 0, 0);
    }
  };

  dmaB(0, 0);
  __builtin_amdgcn_sched_barrier(0);
  loadA(0, a);
  asm volatile("s_waitcnt vmcnt(4)" ::: "memory");
  __builtin_amdgcn_s_barrier();
  __builtin_amdgcn_sched_barrier(0);

  for (int t = 0; t < KT64 - 1; ++t) {
    const int cur = t & 1, nxt = cur ^ 1;
    dmaB(t + 1, nxt);
    __builtin_amdgcn_sched_barrier(0);
    loadA(t + 1, na);
    mfmaStep(cur, a);
    asm volatile("s_waitcnt vmcnt(4)" ::: "memory");
    __builtin_amdgcn_s_barrier();
    __builtin_amdgcn_sched_barrier(0);
#pragma unroll
    for (int q = 0; q < 4; ++q) a[q] = na[q];
  }
  mfmaStep((KT64 - 1) & 1, a);

  // epilogue: C/D map col=lane&15, row=(lane>>4)*4+i  [m89-verified]
#pragma unroll
  for (int n = 0; n < 8; ++n) {
    int col = n * 16 + lr;
    if (col < 64) {
      float badd = brs[col] + b1[col];
#pragma unroll
      for (int i = 0; i < 4; ++i) {
        int row = m0 + wid * 16 + lg * 4 + i;
        if (row < N_NODES) Hres[(size_t)row * 64 + col] = acc[n][i] + badd;
      }
    } else {
#pragma unroll
      for (int i = 0; i < 4; ++i) {
        int row = m0 + wid * 16 + lg * 4 + i;
        if (row < N_NODES) Hatt[(size_t)row * 64 + (col - 64)] = f2bf(acc[n][i]);
      }
    }
  }
  // fused attn1 logits: head h = ((n-4)*16+lr)>>3, channel c = lr&7.
#pragma unroll
  for (int n = 4; n < 8; ++n) {
    int acol = (n - 4) * 16 + lr;
    int h = acol >> 3, c = acol & 7;
    float wsrc = att_src1[h * 8 + c];
    float wdst = att_dst1[h * 8 + c];
#pragma unroll
    for (int i = 0; i < 4; ++i) {
      float v = acc[n][i];
      float s = v * wsrc, d = v * wdst;
      s += __shfl_xor(s, 1); s += __shfl_xor(s, 2); s += __shfl_xor(s, 4);
      d += __shfl_xor(d, 1); d += __shfl_xor(d, 2); d += __shfl_xor(d, 4);
      int row = m0 + wid * 16 + lg * 4 + i;
      if ((lane & 7) == 0 && row < N_NODES) {
        a_src[(unsigned)(row * 8 + h)] = s * LOG2E;
        dinv1[(unsigned)(row * 8 + h)] = make_float2(d * LOG2E, 0.f);
      }
    }
  }
}

// ---------------- layer-1 aggregation FUSED with layer-2 prep ---------------
__global__ __launch_bounds__(256) void k_layer1f(const ushort* __restrict__ esrc,
    const int* __restrict__ cursor,
    const float* __restrict__ Hres, const ushort* __restrict__ Hatt,
    const float* __restrict__ a_src, float2* __restrict__ dinv1,
    const float* __restrict__ w2, const float* __restrict__ att_src2,
    const float* __restrict__ att_dst2, ushort* __restrict__ h2b,
    float* __restrict__ a_src2, float2* __restrict__ dinv2) {
  __shared__ float w2s[64 * 30];
  __shared__ float xs[4][64];
  for (int i = threadIdx.x; i < 64 * 30; i += 256) w2s[i] = w2[i];
  if (blockIdx.x == 0) {
    if (threadIdx.x < 32) h2b[(unsigned)(SENT * 32 + threadIdx.x)] = 0;
    if (threadIdx.x == 32) a_src2[SENT] = NEG_BIG;
  }
  __syncthreads();
  int wave = threadIdx.x >> 6, lane = threadIdx.x & 63;
  int n = blockIdx.x * 4 + wave;
  if (n >= N_NODES) return;
  int hd = lane >> 3;
  int eo = lane & 7;
  float adn = dinv1[(unsigned)(n * 8 + hd)].x;
  int start = n * ROWCAP, end = start + ((cursor[n] + 7) & ~7);
  float denom = 0.f, msg = 0.f;
  for (int p = start; p < end; p += 8) {
    unsigned sl = esrc[p + eo];
    float evm = lexp2(a_src[sl * 8 + hd] + adn);
    ushort8 v = *(const ushort8*)&esrc[p];
    ushort hu[8];
#pragma unroll
    for (int i = 0; i < 8; ++i) hu[i] = Hatt[(unsigned)v[i] * 64 + lane];
#pragma unroll
    for (int i = 0; i < 8; ++i) {
      float ev = __shfl(evm, hd * 8 + i);
      denom += ev;
      msg = fmaf(ev, bf2f(hu[i]), msg);
    }
  }
  float invd = 1.f / (denom + 1e-16f);
  float x1v = msg * invd + Hres[(unsigned)(n * 64 + lane)];
  x1v = x1v > 0.f ? x1v : __expf(x1v) - 1.f;
  if (eo == 0) dinv1[(unsigned)(n * 8 + hd)].y = invd;

  xs[wave][lane] = x1v;
  float acc2 = 0.f;
  if (lane < 30) {
#pragma unroll 8
    for (int k = 0; k < 64; ++k) acc2 = fmaf(xs[wave][k], w2s[k * 30 + lane], acc2);
  }
  float as = (lane < 30) ? acc2 * att_src2[lane] : 0.f;
  float ad = (lane < 30) ? acc2 * att_dst2[lane] : 0.f;
  for (int off = 1; off < 64; off <<= 1) {
    as += __shfl_xor(as, off);
    ad += __shfl_xor(ad, off);
  }
  if (lane == 0) { a_src2[n] = as * LOG2E; dinv2[n] = make_float2(ad * LOG2E, 0.f); }
  if (lane < 32) h2b[(unsigned)(n * 32 + lane)] = (lane < 30) ? f2bf(acc2) : (ushort)0;
}

// ---------------- layer-2 aggregation + concurrent alpha1 -------------------
__global__ __launch_bounds__(256) void k_l2a1(const ushort* __restrict__ esrc,
    const int* __restrict__ cursor,
    const ushort* __restrict__ h2b, const float* __restrict__ a_src2,
    float2* __restrict__ dinv2, const float* __restrict__ b2,
    float* __restrict__ out0, const int* __restrict__ ei,
    const float* __restrict__ a_src1, const float2* __restrict__ dinv1,
    float* __restrict__ alpha1) {
  if (blockIdx.x >= L2_BLOCKS) {                   // ---- alpha1 path ----
    int i = (blockIdx.x - L2_BLOCKS) * 256 + threadIdx.x;
    if (i < E8) {
      int e = i >> 3, h = i & 7;
      int s, d;
      if (e < NUM_EDGES) { s = ei[e]; d = ei[NUM_EDGES + e]; }
      else { s = d = e - NUM_EDGES; }
      float2 di = dinv1[(unsigned)(d * 8 + h)];
      alpha1[i] = lexp2(a_src1[(unsigned)(s * 8 + h)] + di.x) * di.y;
    }
    return;
  }
  // ---- layer-2 path ----
  int wave = threadIdx.x >> 6, lane = threadIdx.x & 63;
  int n = blockIdx.x * 4 + wave;
  if (n >= N_NODES) return;
  float adn = dinv2[n].x;
  int start = n * ROWCAP, end = start + ((cursor[n] + 7) & ~7);
  int cls = lane & 31;
  float denom = 0.f, msg = 0.f;
  for (int p = start; p < end; p += 8) {
    unsigned sl = esrc[p + (lane & 7)];
    float evm = lexp2(a_src2[sl] + adn);
    ushort8 v = *(const ushort8*)&esrc[p];
    ushort hv[8];
#pragma unroll
    for (int i = 0; i < 8; ++i) hv[i] = h2b[(unsigned)v[i] * 32 + cls];
#pragma unroll
    for (int i = 0; i < 8; ++i) {
      float ev = __shfl(evm, i);
      denom += ev;
      msg = fmaf(ev, bf2f(hv[i]), msg);
    }
  }
  float invd = 1.f / (denom + 1e-16f);
  bool act = lane < 30;
  float o = act ? msg * invd + b2[lane] : 0.f;
  float x2 = o > 0.f ? o : __expf(o) - 1.f;
  float mv = act ? x2 : -1e30f;
  for (int off = 1; off < 64; off <<= 1) mv = fmaxf(mv, __shfl_xor(mv, off));
  float ex = act ? __expf(x2 - mv) : 0.f;
  for (int off = 1; off < 64; off <<= 1) ex += __shfl_xor(ex, off);
  if (act) out0[(size_t)n * 30 + lane] = x2 - mv - __logf(ex);
  if (lane == 0) dinv2[n].y = invd;
}

// ---------------- alpha2: edge-order, coalesced -----------------------------
__global__ __launch_bounds__(256) void k_alpha2(const int* __restrict__ ei,
    const float* __restrict__ a_src2, const float2* __restrict__ dinv2,
    float* __restrict__ alpha2) {
  int i = blockIdx.x * 256 + threadIdx.x;
  if (i >= E_TOTAL) return;
  int s, d;
  if (i < NUM_EDGES) { s = ei[i]; d = ei[NUM_EDGES + i]; }
  else { s = d = i - NUM_EDGES; }
  float2 dj = dinv2[(unsigned)d];
  alpha2[i] = lexp2(a_src2[(unsigned)s] + dj.x) * dj.y;
}

extern "C" void kernel_launch(void* const* d_in, const int* in_sizes, int n_in,
                              void* d_out, int out_size, void* d_ws, size_t ws_size,
                              hipStream_t stream) {
  const float* x        = (const float*)d_in[0];
  const int*   ei       = (const int*)d_in[1];
  const float* w_res    = (const float*)d_in[2];
  const float* b_res    = (const float*)d_in[3];
  const float* w1       = (const float*)d_in[4];
  const float* att_src1 = (const float*)d_in[5];
  const float* att_dst1 = (const float*)d_in[6];
  const float* b1       = (const float*)d_in[7];
  const float* w2       = (const float*)d_in[8];
  const float* att_src2 = (const float*)d_in[9];
  const float* att_dst2 = (const float*)d_in[10];
  const float* b2       = (const float*)d_in[11];

  float* ws = (float*)d_ws;
  float* Hres    = ws;                                     // [N][64]  12.8 MB
  ushort* esrc   = (ushort*)(Hres + (size_t)N_NODES * 64); // [N][128] ushort 12.8 MB
  float* a_src1  = (float*)(esrc + (size_t)N_NODES * ROWCAP); // [(N+1)][8]
  float2* dinv1  = (float2*)(a_src1 + (size_t)(N_NODES + 1) * 8); // [N][8]
  float* a_src2  = (float*)(dinv1 + (size_t)N_NODES * 8);  // [N+1]
  float2* dinv2  = (float2*)(a_src2 + N_NODES + 1);        // [N]
  ushort* Hatt   = (ushort*)(dinv2 + N_NODES);             // [(N+1)][64]
  ushort* h2b    = Hatt + (size_t)(N_NODES + 1) * 64;      // [(N+1)][32]
  ushort* Bp     = h2b + (size_t)(N_NODES + 1) * 32 + 32;  // 1 MB
  int*   cursor  = (int*)(Bp + (size_t)KT32 * 4096 + 64);  // [N]

  float* out0   = (float*)d_out;                           // [N][30]
  float* alpha1 = out0 + (size_t)N_NODES * 30;             // [E_TOTAL][8]
  float* alpha2 = alpha1 + (size_t)E8;                     // [E_TOTAL]

  k_init<<<(N_NODES * ROWCAP / 8 + 255) / 256, 256, 0, stream>>>(esrc, w_res, w1,
                                                                 Bp, cursor,
                                                                 Hatt, a_src1);
  k_gemm_fill<<<GEMM_BLOCKS + FILL_BLOCKS, 256, 0, stream>>>(x, Bp, b_res, b1,
                                                             Hres, Hatt, ei,
                                                             cursor, esrc,
                                                             att_src1, att_dst1,
                                                             a_src1, dinv1);
  k_layer1f<<<(N_NODES + 3) / 4, 256, 0, stream>>>(esrc, cursor, Hres, Hatt,
                                                   a_src1, dinv1, w2, att_src2,
                                                   att_dst2, h2b, a_src2, dinv2);
  k_l2a1<<<L2_BLOCKS + A1_BLOCKS, 256, 0, stream>>>(esrc, cursor, h2b, a_src2,
                                                    dinv2, b2, out0, ei,
                                                    a_src1, dinv1, alpha1);
  k_alpha2<<<(E_TOTAL + 255) / 256, 256, 0, stream>>>(ei, a_src2, dinv2, alpha2);
}